// Round 12
// baseline (458.630 us; speedup 1.0000x reference)
//
#include <hip/hip_runtime.h>
#include <hip/hip_fp16.h>

// N=1e6 nodes, E=32e6 edges.
// out[i] = (sum_{e: dst=i} h2[src_e]) / max(deg_in(i),1) * Wsage
// h2[v] = sum_j W2[j]*relu(W1[j]*x[v]+b1[j]) + b2
//
// R11 (on R10): discriminating experiment for the ~157us gather cost in
// aggregate. Mechanism (a) L1 miss-path churn -> fix: nontemporal gather
// (evict-first) + 8-wide run walk (more misses in flight). Mechanism (b)
// intrinsic TA divergent-address rate -> unchanged, and next round converts
// gathers to LDS lookups via src-binned two-level sort.
// Scatter stays R8 (pure int sort, no gather, ~65us).
//
// ws layout: entries uint[NTILES*TILE]; index int[257*NTILES];
//            partial double[NSUB*NBINS*4096]; h2f16 ushort[n]; flag int.
// Fallback (ws too small or n >= 2^20): R1 packed f64-atomic path.

#define NBINS    256
#define BSHIFT   12
#define DMASK    4095
#define SRCBITS  20
#define SRCMASK  ((1u << SRCBITS) - 1)
#define NBLK     1024
#define STHREADS 512
#define EPT      16
#define TILE     (STHREADS * EPT)   // 8192
#define NSUB     4
#define WALK     8                  // runs walked simultaneously per 32-lane group
#define PACK_SCALE 1048576.0        // 2^20

// ---- dtype probe: int64 edge_index => every odd 32-bit word is 0 ----
__global__ void detect_dtype_kernel(const int* __restrict__ ei, int* __restrict__ flag) {
    if (threadIdx.x == 0 && blockIdx.x == 0) {
        int is64 = 1;
        for (int i = 1; i < 256; i += 2) {
            if (ei[i] != 0) { is64 = 0; break; }
        }
        *flag = is64;
    }
}

__global__ void node_kernel(const float* __restrict__ x,
                            const float* __restrict__ W1,
                            const float* __restrict__ b1,
                            const float* __restrict__ W2,
                            const float* __restrict__ b2,
                            unsigned short* __restrict__ h2f16,
                            int n) {
    int i = blockIdx.x * blockDim.x + threadIdx.x;
    if (i >= n) return;
    float xi = x[i];
    float acc = b2[0];
#pragma unroll
    for (int j = 0; j < 4; ++j) {
        float t = fmaxf(W1[j] * xi + b1[j], 0.0f);
        acc += W2[j] * t;
    }
    h2f16[i] = __half_as_ushort(__float2half(acc));
}

// P1: one-pass tile-sorted scatter into block-private slots + bin-major index.
// Entry = (dlow << 20) | src. No value gather here.
__global__ void __launch_bounds__(STHREADS)
scatter_tile_kernel(const int* __restrict__ ei,
                    unsigned int* __restrict__ entries,
                    int* __restrict__ index,   // [257][ntiles]
                    const int* __restrict__ flag,
                    long long E, long long chunk, int tpb, int ntiles) {
    __shared__ unsigned int ents[TILE];
    __shared__ int hist[NBINS];
    __shared__ int toff[NBINS];
    __shared__ int s_total;

    const int t = threadIdx.x;
    long long start = (long long)blockIdx.x * chunk;
    long long end   = start + chunk; if (end > E) end = E;
    const int is64 = *flag;
    const long long* e64 = (const long long*)ei;

    int ti = 0;
    for (long long tbase = start; tbase < end; tbase += TILE, ++ti) {
        for (int i = t; i < NBINS; i += STHREADS) hist[i] = 0;
        __syncthreads();

        // ---- phase 1: load all src/dst (independent loads in flight) ----
        int sk[EPT], dk[EPT];
        if (is64) {
#pragma unroll
            for (int k = 0; k < EPT; ++k) {
                long long e = tbase + (long long)k * STHREADS + t;
                if (e < end) {
                    sk[k] = (int)__builtin_nontemporal_load(&e64[e]);
                    dk[k] = (int)__builtin_nontemporal_load(&e64[E + e]);
                } else { sk[k] = 0; dk[k] = -1; }
            }
        } else {
#pragma unroll
            for (int k = 0; k < EPT; ++k) {
                long long e = tbase + (long long)k * STHREADS + t;
                if (e < end) {
                    sk[k] = __builtin_nontemporal_load(&ei[e]);
                    dk[k] = __builtin_nontemporal_load(&ei[E + e]);
                } else { sk[k] = 0; dk[k] = -1; }
            }
        }

        // ---- phase 2: rank within (tile, bin) ----
        int rk[EPT];
#pragma unroll
        for (int k = 0; k < EPT; ++k)
            if (dk[k] >= 0) rk[k] = atomicAdd(&hist[dk[k] >> BSHIFT], 1);
        __syncthreads();

        // ---- exclusive scan over 256 bins: wave 0 only, shfl scan ----
        if (t < 64) {
            const int base = t * 4;
            int a0 = hist[base], a1 = hist[base + 1],
                a2 = hist[base + 2], a3 = hist[base + 3];
            int s  = a0 + a1 + a2 + a3;
            int sc = s;
#pragma unroll
            for (int off = 1; off < 64; off <<= 1) {
                int up = __shfl_up(sc, off, 64);
                if (t >= off) sc += up;
            }
            int excl = sc - s;
            toff[base]     = excl;
            toff[base + 1] = excl + a0;
            toff[base + 2] = excl + a0 + a1;
            toff[base + 3] = excl + a0 + a1 + a2;
            if (t == 63) s_total = sc;
        }
        __syncthreads();

        // ---- phase 3: place bin-sorted in LDS ----
#pragma unroll
        for (int k = 0; k < EPT; ++k) {
            if (dk[k] >= 0) {
                int slot = toff[dk[k] >> BSHIFT] + rk[k];
                ents[slot] = ((unsigned int)(dk[k] & DMASK) << SRCBITS)
                           | (unsigned int)sk[k];
            }
        }
        __syncthreads();

        // ---- phase 4: vectorized coalesced copy-out + index row ----
        const int tilecount = s_total;
        const int g = blockIdx.x * tpb + ti;
        unsigned int* gout = entries + (long long)g * TILE;
        const int tc4 = (tilecount + 3) & ~3;
        for (int j = t * 4; j < tc4; j += STHREADS * 4) {
            uint4 val = *(const uint4*)&ents[j];     // ds_read_b128
            *(uint4*)&gout[j] = val;                 // dwordx4 store
        }
        if (t < NBINS)
            __builtin_nontemporal_store(toff[t], &index[(long long)t * ntiles + g]);
        else if (t == NBINS)
            __builtin_nontemporal_store(tilecount, &index[(long long)NBINS * ntiles + g]);
        __syncthreads();
    }
}

// P2: per-(bin,sub) aggregation; each 32-lane group walks WALK runs at once.
// Gathers are nontemporal (bypass/evict-first L1). grid = NBINS*NSUB, 512 thr.
__global__ void __launch_bounds__(512)
aggregate_kernel(const unsigned int* __restrict__ entries,
                 const int* __restrict__ index,
                 const unsigned short* __restrict__ h2f16,
                 double* __restrict__ partial,   // [NSUB*NBINS][4096]
                 int ntiles) {
    __shared__ double acc[4096];
    const int b   = blockIdx.x >> 2;
    const int sub = blockIdx.x & 3;
    const int t   = threadIdx.x;
    for (int i = t; i < 4096; i += 512) acc[i] = 0.0;
    __syncthreads();

    const int quarter = ntiles >> 2;     // runs per sub-block
    const int gbase   = sub * quarter;
    const int grp = t >> 5;              // 16 groups of 32 lanes
    const int hl  = t & 31;
    const int* __restrict__ rowS = index + (long long)b * ntiles;
    const int* __restrict__ rowE = index + (long long)(b + 1) * ntiles;

    for (int g = gbase + grp * WALK; g < gbase + quarter; g += 16 * WALK) {
        int s[WALK], e[WALK], idx[WALK];
#pragma unroll
        for (int q = 0; q < WALK; ++q) {
            s[q] = rowS[g + q];
            e[q] = rowE[g + q];
            idx[q] = s[q] + hl;
        }

        bool any = true;
        while (any) {
            any = false;
            unsigned int ev[WALK];
            bool act[WALK];
            // phase A: WALK independent entry loads in flight
#pragma unroll
            for (int q = 0; q < WALK; ++q) {
                act[q] = idx[q] < e[q];
                const unsigned int* run = entries + (long long)(g + q) * TILE;
                ev[q] = act[q] ? __builtin_nontemporal_load(&run[idx[q]]) : 0u;
            }
            // phase B: WALK independent NONTEMPORAL gathers in flight
            unsigned short hv[WALK];
#pragma unroll
            for (int q = 0; q < WALK; ++q)
                hv[q] = __builtin_nontemporal_load(&h2f16[ev[q] & SRCMASK]);
            // phase C: WALK ds_add_f64
#pragma unroll
            for (int q = 0; q < WALK; ++q) {
                if (act[q]) {
                    atomicAdd(&acc[ev[q] >> SRCBITS],
                              (double)__half2float(__ushort_as_half(hv[q])) + PACK_SCALE);
                    idx[q] += 32;
                    if (idx[q] < e[q]) any = true;
                }
            }
        }
    }
    __syncthreads();

    double* p = partial + (long long)blockIdx.x * 4096;
    for (int i = t; i < 4096; i += 512)
        __builtin_nontemporal_store(acc[i], &p[i]);
}

// P3: finalize — merge NSUB partials per node, decode, write out.
__global__ void finalize_kernel(const double* __restrict__ partial,
                                const float* __restrict__ Wsage,
                                float* __restrict__ out,
                                int n) {
    int i = blockIdx.x * blockDim.x + threadIdx.x;
    if (i >= n) return;
    int b    = i >> BSHIFT;
    int dlow = i & DMASK;
    const double* p = partial + (long long)(b * NSUB) * 4096 + dlow;
    double v = p[0] + p[4096] + p[2 * 4096] + p[3 * 4096];
    double cnt = nearbyint(v * (1.0 / PACK_SCALE));
    double agg = v - cnt * PACK_SCALE;
    out[i] = (float)(agg / fmax(cnt, 1.0)) * Wsage[0];
}

// ---------------- fallback path (R1 packed-atomic) ----------------

__global__ void node_f32_kernel(const float* __restrict__ x,
                                const float* __restrict__ W1,
                                const float* __restrict__ b1,
                                const float* __restrict__ W2,
                                const float* __restrict__ b2,
                                float* __restrict__ h2,
                                int n) {
    int i = blockIdx.x * blockDim.x + threadIdx.x;
    if (i >= n) return;
    float xi = x[i];
    float acc = b2[0];
#pragma unroll
    for (int j = 0; j < 4; ++j) {
        float t = fmaxf(W1[j] * xi + b1[j], 0.0f);
        acc += W2[j] * t;
    }
    h2[i] = acc;
}

__global__ void zero_packed_kernel(double* __restrict__ packed, int n) {
    int i = blockIdx.x * blockDim.x + threadIdx.x;
    if (i < n) packed[i] = 0.0;
}

__global__ void edge_atomic_kernel(const int* __restrict__ ei,
                                   const float* __restrict__ h2,
                                   double* __restrict__ packed,
                                   const int* __restrict__ flag,
                                   long long E) {
    long long i      = (long long)blockIdx.x * blockDim.x + threadIdx.x;
    long long stride = (long long)gridDim.x * blockDim.x;
    const int is64 = *flag;
    if (is64) {
        const long long* e64 = (const long long*)ei;
        for (long long e = i; e < E; e += stride) {
            int s = (int)e64[e];
            int d = (int)e64[E + e];
            atomicAdd(&packed[d], (double)h2[s] + PACK_SCALE);
        }
    } else {
        for (long long e = i; e < E; e += stride) {
            int s = ei[e];
            int d = ei[E + e];
            atomicAdd(&packed[d], (double)h2[s] + PACK_SCALE);
        }
    }
}

__global__ void out_packed_kernel(const double* __restrict__ packed,
                                  const float* __restrict__ Wsage,
                                  float* __restrict__ out,
                                  int n) {
    int i = blockIdx.x * blockDim.x + threadIdx.x;
    if (i >= n) return;
    double v   = packed[i];
    double cnt = nearbyint(v * (1.0 / PACK_SCALE));
    double agg = v - cnt * PACK_SCALE;
    out[i] = (float)(agg / fmax(cnt, 1.0)) * Wsage[0];
}

extern "C" void kernel_launch(void* const* d_in, const int* in_sizes, int n_in,
                              void* d_out, int out_size, void* d_ws, size_t ws_size,
                              hipStream_t stream) {
    const float* x     = (const float*)d_in[0];
    const int*   ei    = (const int*)d_in[1];
    const float* W1    = (const float*)d_in[2];
    const float* b1    = (const float*)d_in[3];
    const float* W2    = (const float*)d_in[4];
    const float* b2    = (const float*)d_in[5];
    const float* Wsage = (const float*)d_in[6];

    const int       n = in_sizes[0];                 // 1,000,000
    const long long E = (long long)in_sizes[1] / 2;  // 32,000,000

    const long long chunk  = (E + NBLK - 1) / NBLK;            // 31250
    const int       tpb    = (int)((chunk + TILE - 1) / TILE); // 4
    const int       ntiles = NBLK * tpb;                       // 4096

    // ws layout
    const size_t entries_b = (size_t)ntiles * TILE * 4;
    const size_t index_b   = (size_t)(NBINS + 1) * ntiles * 4;
    const size_t partial_b = (size_t)NSUB * NBINS * 4096 * 8;
    const size_t h2_b      = (size_t)n * 2;
    const size_t need      = entries_b + index_b + partial_b + h2_b + 64;

    if (ws_size >= need && n <= (1 << SRCBITS) && (ntiles % (NSUB * 16 * WALK)) == 0) {
        unsigned int*   entries = (unsigned int*)d_ws;
        int*            index   = (int*)((char*)d_ws + entries_b);
        double*         partial = (double*)((char*)d_ws + entries_b + index_b);
        unsigned short* h2f16   = (unsigned short*)((char*)d_ws + entries_b + index_b + partial_b);
        int*            flag    = (int*)((char*)d_ws + entries_b + index_b + partial_b + h2_b);

        detect_dtype_kernel<<<1, 64, 0, stream>>>(ei, flag);
        {
            int threads = 256;
            int blocks  = (n + threads - 1) / threads;
            node_kernel<<<blocks, threads, 0, stream>>>(x, W1, b1, W2, b2, h2f16, n);
        }
        scatter_tile_kernel<<<NBLK, STHREADS, 0, stream>>>(ei, entries, index,
                                                           flag, E, chunk, tpb, ntiles);
        aggregate_kernel<<<NBINS * NSUB, 512, 0, stream>>>(entries, index, h2f16,
                                                           partial, ntiles);
        {
            int threads = 256;
            int blocks  = (n + threads - 1) / threads;
            finalize_kernel<<<blocks, threads, 0, stream>>>(partial, Wsage,
                                                            (float*)d_out, n);
        }
    } else {
        // fallback: R1 packed-atomic path
        double* packed = (double*)d_ws;
        float*  h2     = (float*)d_out;
        int*    flag   = (int*)(packed + n);

        detect_dtype_kernel<<<1, 64, 0, stream>>>(ei, flag);
        {
            int threads = 256;
            int blocks  = (n + threads - 1) / threads;
            node_f32_kernel<<<blocks, threads, 0, stream>>>(x, W1, b1, W2, b2, h2, n);
            zero_packed_kernel<<<blocks, threads, 0, stream>>>(packed, n);
        }
        edge_atomic_kernel<<<4096, 256, 0, stream>>>(ei, h2, packed, flag, E);
        {
            int threads = 256;
            int blocks  = (n + threads - 1) / threads;
            out_packed_kernel<<<blocks, threads, 0, stream>>>(packed, Wsage,
                                                              (float*)d_out, n);
        }
    }
}

// Round 13
// 263.329 us; speedup vs baseline: 1.7417x; 1.7417x over previous
//
#include <hip/hip_runtime.h>
#include <hip/hip_fp16.h>

// N=1e6 nodes, E=32e6 edges.
// out[i] = (sum_{e: dst=i} h2[src_e]) / max(deg_in(i),1) * Wsage
// h2[v] = sum_j W2[j]*relu(W1[j]*x[v]+b1[j]) + b2
//
// R12: revert to the best measured config (R6-style value-in-entry) after
// R11 proved the gather is L2->L1 line-bandwidth bound (4GB of 128B lines,
// ~116us) and placement-invariant. Cheapest placement = scatter (16-deep
// ILP, costs ~133us there vs ~157us in aggregate).
//  - node_kernel absorbs the dtype probe (one launch fewer).
//  - aggregate: R10's 4-walk structure, NSUB=4, NO gather (val in entry),
//    ONE packed f64 LDS atomic per entry.
//  - nontemporal ONLY on streams (ei, entries, partials) — NEVER on the
//    h2 table (R11's lesson: it evicts the table from L2).
//
// ws layout: entries uint[NTILES*TILE]; index int[257*NTILES];
//            partial double[NSUB*NBINS*4096]; h2f16 ushort[n]; flag int.
// Fallback (ws too small): R1 packed f64-atomic path.

#define NBINS    256
#define BSHIFT   12
#define DMASK    4095
#define NBLK     1024
#define STHREADS 512
#define EPT      16
#define TILE     (STHREADS * EPT)   // 8192
#define NSUB     4
#define PACK_SCALE 1048576.0        // 2^20

// node MLP + dtype probe (block 0 lane 0; int64 => odd 32-bit words all 0)
__global__ void node_kernel(const float* __restrict__ x,
                            const float* __restrict__ W1,
                            const float* __restrict__ b1,
                            const float* __restrict__ W2,
                            const float* __restrict__ b2,
                            const int* __restrict__ ei,
                            unsigned short* __restrict__ h2f16,
                            int* __restrict__ flag,
                            int n) {
    int i = blockIdx.x * blockDim.x + threadIdx.x;
    if (i == 0) {
        int is64 = 1;
        for (int k = 1; k < 256; k += 2) {
            if (ei[k] != 0) { is64 = 0; break; }
        }
        *flag = is64;
    }
    if (i >= n) return;
    float xi = x[i];
    float acc = b2[0];
#pragma unroll
    for (int j = 0; j < 4; ++j) {
        float t = fmaxf(W1[j] * xi + b1[j], 0.0f);
        acc += W2[j] * t;
    }
    h2f16[i] = __half_as_ushort(__float2half(acc));
}

// P1: one-pass tile-sorted scatter. Entry = (dlow:12 << 16) | fp16(h2[src]).
// Gather lives here: 16 independent gathers in flight per thread.
__global__ void __launch_bounds__(STHREADS)
scatter_tile_kernel(const int* __restrict__ ei,
                    const unsigned short* __restrict__ h2f16,
                    unsigned int* __restrict__ entries,
                    int* __restrict__ index,   // [257][ntiles]
                    const int* __restrict__ flag,
                    long long E, long long chunk, int tpb, int ntiles) {
    __shared__ unsigned int ents[TILE];
    __shared__ int hist[NBINS];
    __shared__ int toff[NBINS];
    __shared__ int s_total;

    const int t = threadIdx.x;
    long long start = (long long)blockIdx.x * chunk;
    long long end   = start + chunk; if (end > E) end = E;
    const int is64 = *flag;
    const long long* e64 = (const long long*)ei;

    int ti = 0;
    for (long long tbase = start; tbase < end; tbase += TILE, ++ti) {
        for (int i = t; i < NBINS; i += STHREADS) hist[i] = 0;
        __syncthreads();

        // ---- phase 1: load all src/dst (independent loads in flight) ----
        int sk[EPT], dk[EPT];
        if (is64) {
#pragma unroll
            for (int k = 0; k < EPT; ++k) {
                long long e = tbase + (long long)k * STHREADS + t;
                if (e < end) {
                    sk[k] = (int)__builtin_nontemporal_load(&e64[e]);
                    dk[k] = (int)__builtin_nontemporal_load(&e64[E + e]);
                } else { sk[k] = 0; dk[k] = -1; }
            }
        } else {
#pragma unroll
            for (int k = 0; k < EPT; ++k) {
                long long e = tbase + (long long)k * STHREADS + t;
                if (e < end) {
                    sk[k] = __builtin_nontemporal_load(&ei[e]);
                    dk[k] = __builtin_nontemporal_load(&ei[E + e]);
                } else { sk[k] = 0; dk[k] = -1; }
            }
        }

        // ---- phase 2: gather h2 (TEMPORAL: table must stay L2-resident) ----
        unsigned int hv[EPT];
#pragma unroll
        for (int k = 0; k < EPT; ++k) hv[k] = (unsigned int)h2f16[sk[k]];

        // ---- phase 3: rank within (tile, bin) ----
        int rk[EPT];
#pragma unroll
        for (int k = 0; k < EPT; ++k)
            if (dk[k] >= 0) rk[k] = atomicAdd(&hist[dk[k] >> BSHIFT], 1);
        __syncthreads();

        // ---- exclusive scan over 256 bins: wave 0 only, shfl scan ----
        if (t < 64) {
            const int base = t * 4;
            int a0 = hist[base], a1 = hist[base + 1],
                a2 = hist[base + 2], a3 = hist[base + 3];
            int s  = a0 + a1 + a2 + a3;
            int sc = s;
#pragma unroll
            for (int off = 1; off < 64; off <<= 1) {
                int up = __shfl_up(sc, off, 64);
                if (t >= off) sc += up;
            }
            int excl = sc - s;
            toff[base]     = excl;
            toff[base + 1] = excl + a0;
            toff[base + 2] = excl + a0 + a1;
            toff[base + 3] = excl + a0 + a1 + a2;
            if (t == 63) s_total = sc;
        }
        __syncthreads();

        // ---- phase 4: place bin-sorted in LDS ----
#pragma unroll
        for (int k = 0; k < EPT; ++k) {
            if (dk[k] >= 0) {
                int slot = toff[dk[k] >> BSHIFT] + rk[k];
                ents[slot] = ((unsigned int)(dk[k] & DMASK) << 16) | hv[k];
            }
        }
        __syncthreads();

        // ---- phase 5: vectorized coalesced copy-out + index row ----
        const int tilecount = s_total;
        const int g = blockIdx.x * tpb + ti;
        unsigned int* gout = entries + (long long)g * TILE;
        const int tc4 = (tilecount + 3) & ~3;
        for (int j = t * 4; j < tc4; j += STHREADS * 4) {
            uint4 val = *(const uint4*)&ents[j];     // ds_read_b128
            *(uint4*)&gout[j] = val;                 // dwordx4 store
        }
        if (t < NBINS)
            __builtin_nontemporal_store(toff[t], &index[(long long)t * ntiles + g]);
        else if (t == NBINS)
            __builtin_nontemporal_store(tilecount, &index[(long long)NBINS * ntiles + g]);
        __syncthreads();
    }
}

// P2: per-(bin,sub) aggregation; 4 runs walked at once per 32-lane group;
// value decoded from entry (no gather); ONE packed f64 LDS atomic per entry.
// grid = NBINS*NSUB, 512 threads.
__global__ void __launch_bounds__(512)
aggregate_kernel(const unsigned int* __restrict__ entries,
                 const int* __restrict__ index,
                 double* __restrict__ partial,   // [NSUB*NBINS][4096]
                 int ntiles) {
    __shared__ double acc[4096];
    const int b   = blockIdx.x >> 2;
    const int sub = blockIdx.x & 3;
    const int t   = threadIdx.x;
    for (int i = t; i < 4096; i += 512) acc[i] = 0.0;
    __syncthreads();

    const int quarter = ntiles >> 2;     // runs per sub-block
    const int gbase   = sub * quarter;
    const int grp = t >> 5;              // 16 groups of 32 lanes
    const int hl  = t & 31;
    const int* __restrict__ rowS = index + (long long)b * ntiles;
    const int* __restrict__ rowE = index + (long long)(b + 1) * ntiles;

    for (int g = gbase + grp * 4; g < gbase + quarter; g += 64) {
        int s[4], e[4], idx[4];
#pragma unroll
        for (int q = 0; q < 4; ++q) {
            s[q] = rowS[g + q];
            e[q] = rowE[g + q];
            idx[q] = s[q] + hl;
        }

        bool any = true;
        while (any) {
            any = false;
            unsigned int ev[4];
            bool act[4];
#pragma unroll
            for (int q = 0; q < 4; ++q) {
                act[q] = idx[q] < e[q];
                const unsigned int* run = entries + (long long)(g + q) * TILE;
                ev[q] = act[q] ? __builtin_nontemporal_load(&run[idx[q]]) : 0u;
            }
#pragma unroll
            for (int q = 0; q < 4; ++q) {
                if (act[q]) {
                    float v = __half2float(__ushort_as_half((unsigned short)(ev[q] & 0xFFFFu)));
                    atomicAdd(&acc[ev[q] >> 16], (double)v + PACK_SCALE);  // ds_add_f64
                    idx[q] += 32;
                    if (idx[q] < e[q]) any = true;
                }
            }
        }
    }
    __syncthreads();

    double* p = partial + (long long)blockIdx.x * 4096;
    for (int i = t; i < 4096; i += 512)
        __builtin_nontemporal_store(acc[i], &p[i]);
}

// P3: finalize — merge NSUB partials per node, decode, write out.
__global__ void finalize_kernel(const double* __restrict__ partial,
                                const float* __restrict__ Wsage,
                                float* __restrict__ out,
                                int n) {
    int i = blockIdx.x * blockDim.x + threadIdx.x;
    if (i >= n) return;
    int b    = i >> BSHIFT;
    int dlow = i & DMASK;
    const double* p = partial + (long long)(b * NSUB) * 4096 + dlow;
    double v = p[0] + p[4096] + p[2 * 4096] + p[3 * 4096];
    double cnt = nearbyint(v * (1.0 / PACK_SCALE));
    double agg = v - cnt * PACK_SCALE;
    out[i] = (float)(agg / fmax(cnt, 1.0)) * Wsage[0];
}

// ---------------- fallback path (R1 packed-atomic) ----------------

__global__ void node_f32_kernel(const float* __restrict__ x,
                                const float* __restrict__ W1,
                                const float* __restrict__ b1,
                                const float* __restrict__ W2,
                                const float* __restrict__ b2,
                                const int* __restrict__ ei,
                                float* __restrict__ h2,
                                int* __restrict__ flag,
                                int n) {
    int i = blockIdx.x * blockDim.x + threadIdx.x;
    if (i == 0) {
        int is64 = 1;
        for (int k = 1; k < 256; k += 2) {
            if (ei[k] != 0) { is64 = 0; break; }
        }
        *flag = is64;
    }
    if (i >= n) return;
    float xi = x[i];
    float acc = b2[0];
#pragma unroll
    for (int j = 0; j < 4; ++j) {
        float t = fmaxf(W1[j] * xi + b1[j], 0.0f);
        acc += W2[j] * t;
    }
    h2[i] = acc;
}

__global__ void zero_packed_kernel(double* __restrict__ packed, int n) {
    int i = blockIdx.x * blockDim.x + threadIdx.x;
    if (i < n) packed[i] = 0.0;
}

__global__ void edge_atomic_kernel(const int* __restrict__ ei,
                                   const float* __restrict__ h2,
                                   double* __restrict__ packed,
                                   const int* __restrict__ flag,
                                   long long E) {
    long long i      = (long long)blockIdx.x * blockDim.x + threadIdx.x;
    long long stride = (long long)gridDim.x * blockDim.x;
    const int is64 = *flag;
    if (is64) {
        const long long* e64 = (const long long*)ei;
        for (long long e = i; e < E; e += stride) {
            int s = (int)e64[e];
            int d = (int)e64[E + e];
            atomicAdd(&packed[d], (double)h2[s] + PACK_SCALE);
        }
    } else {
        for (long long e = i; e < E; e += stride) {
            int s = ei[e];
            int d = ei[E + e];
            atomicAdd(&packed[d], (double)h2[s] + PACK_SCALE);
        }
    }
}

__global__ void out_packed_kernel(const double* __restrict__ packed,
                                  const float* __restrict__ Wsage,
                                  float* __restrict__ out,
                                  int n) {
    int i = blockIdx.x * blockDim.x + threadIdx.x;
    if (i >= n) return;
    double v   = packed[i];
    double cnt = nearbyint(v * (1.0 / PACK_SCALE));
    double agg = v - cnt * PACK_SCALE;
    out[i] = (float)(agg / fmax(cnt, 1.0)) * Wsage[0];
}

extern "C" void kernel_launch(void* const* d_in, const int* in_sizes, int n_in,
                              void* d_out, int out_size, void* d_ws, size_t ws_size,
                              hipStream_t stream) {
    const float* x     = (const float*)d_in[0];
    const int*   ei    = (const int*)d_in[1];
    const float* W1    = (const float*)d_in[2];
    const float* b1    = (const float*)d_in[3];
    const float* W2    = (const float*)d_in[4];
    const float* b2    = (const float*)d_in[5];
    const float* Wsage = (const float*)d_in[6];

    const int       n = in_sizes[0];                 // 1,000,000
    const long long E = (long long)in_sizes[1] / 2;  // 32,000,000

    const long long chunk  = (E + NBLK - 1) / NBLK;            // 31250
    const int       tpb    = (int)((chunk + TILE - 1) / TILE); // 4
    const int       ntiles = NBLK * tpb;                       // 4096

    // ws layout
    const size_t entries_b = (size_t)ntiles * TILE * 4;
    const size_t index_b   = (size_t)(NBINS + 1) * ntiles * 4;
    const size_t partial_b = (size_t)NSUB * NBINS * 4096 * 8;
    const size_t h2_b      = (size_t)n * 2;
    const size_t need      = entries_b + index_b + partial_b + h2_b + 64;

    if (ws_size >= need && (ntiles % (NSUB * 16 * 4)) == 0) {
        unsigned int*   entries = (unsigned int*)d_ws;
        int*            index   = (int*)((char*)d_ws + entries_b);
        double*         partial = (double*)((char*)d_ws + entries_b + index_b);
        unsigned short* h2f16   = (unsigned short*)((char*)d_ws + entries_b + index_b + partial_b);
        int*            flag    = (int*)((char*)d_ws + entries_b + index_b + partial_b + h2_b);

        {
            int threads = 256;
            int blocks  = (n + threads - 1) / threads;
            node_kernel<<<blocks, threads, 0, stream>>>(x, W1, b1, W2, b2, ei,
                                                        h2f16, flag, n);
        }
        scatter_tile_kernel<<<NBLK, STHREADS, 0, stream>>>(ei, h2f16, entries, index,
                                                           flag, E, chunk, tpb, ntiles);
        aggregate_kernel<<<NBINS * NSUB, 512, 0, stream>>>(entries, index,
                                                           partial, ntiles);
        {
            int threads = 256;
            int blocks  = (n + threads - 1) / threads;
            finalize_kernel<<<blocks, threads, 0, stream>>>(partial, Wsage,
                                                            (float*)d_out, n);
        }
    } else {
        // fallback: R1 packed-atomic path
        double* packed = (double*)d_ws;
        float*  h2     = (float*)d_out;
        int*    flag   = (int*)(packed + n);

        {
            int threads = 256;
            int blocks  = (n + threads - 1) / threads;
            node_f32_kernel<<<blocks, threads, 0, stream>>>(x, W1, b1, W2, b2, ei,
                                                            h2, flag, n);
            zero_packed_kernel<<<blocks, threads, 0, stream>>>(packed, n);
        }
        edge_atomic_kernel<<<4096, 256, 0, stream>>>(ei, h2, packed, flag, E);
        {
            int threads = 256;
            int blocks  = (n + threads - 1) / threads;
            out_packed_kernel<<<blocks, threads, 0, stream>>>(packed, Wsage,
                                                              (float*)d_out, n);
        }
    }
}